// Round 2
// baseline (1384.853 us; speedup 1.0000x reference)
//
#include <hip/hip_runtime.h>
#include <cstdint>
#include <cstddef>

constexpr int NN = 50000;
constexpr int NE = 800000;

// ---------------- GEMM NT: C[N,M] = act(A[N,K] @ B[M,K]^T + bias) -------------
// BN=64 rows x BM=64 cols per block, BK=16, 256 threads, 4x4 micro-tile.
// ACT: 0 = none, 1 = elu
template<int ACT>
__global__ __launch_bounds__(256) void gemm_nt(const float* __restrict__ A,
    const float* __restrict__ B, const float* __restrict__ bias,
    float* __restrict__ C, int N, int M, int K)
{
  __shared__ float As[16][64];   // As[k][row]
  __shared__ float Bs[16][64];   // Bs[k][col]
  const int tid = threadIdx.x;
  const int tx = tid & 15, ty = tid >> 4;
  const int row0 = blockIdx.x * 64, col0 = blockIdx.y * 64;
  const int lr = tid >> 2;           // 0..63
  const int kq = (tid & 3) << 2;     // 0,4,8,12
  float acc[4][4] = {};
  for (int k0 = 0; k0 < K; k0 += 16) {
    float4 a = make_float4(0.f,0.f,0.f,0.f), b = make_float4(0.f,0.f,0.f,0.f);
    int gr = row0 + lr;
    if (gr < N) a = *(const float4*)(A + (size_t)gr * K + k0 + kq);
    int gc = col0 + lr;
    if (gc < M) b = *(const float4*)(B + (size_t)gc * K + k0 + kq);
    __syncthreads();   // protect previous iteration's LDS reads
    As[kq+0][lr]=a.x; As[kq+1][lr]=a.y; As[kq+2][lr]=a.z; As[kq+3][lr]=a.w;
    Bs[kq+0][lr]=b.x; Bs[kq+1][lr]=b.y; Bs[kq+2][lr]=b.z; Bs[kq+3][lr]=b.w;
    __syncthreads();
    #pragma unroll
    for (int k = 0; k < 16; ++k) {
      float4 av = *(const float4*)&As[k][ty*4];
      float4 bv = *(const float4*)&Bs[k][tx*4];
      float aa[4] = {av.x,av.y,av.z,av.w};
      float bb[4] = {bv.x,bv.y,bv.z,bv.w};
      #pragma unroll
      for (int i = 0; i < 4; ++i)
        #pragma unroll
        for (int j = 0; j < 4; ++j)
          acc[i][j] += aa[i]*bb[j];
    }
  }
  #pragma unroll
  for (int i = 0; i < 4; ++i) {
    int row = row0 + ty*4 + i;
    if (row >= N) continue;
    #pragma unroll
    for (int j = 0; j < 4; ++j) {
      int col = col0 + tx*4 + j;
      if (col >= M) continue;
      float v = acc[i][j] + bias[col];
      if (ACT == 1) v = v > 0.f ? v : (__expf(v) - 1.f);
      C[(size_t)row*M + col] = v;
    }
  }
}

// ---------------- CSR build (dst-sorted edge permutation) ---------------------
// edge_index arrives as int32 (harness converts integer inputs to int32).
__global__ void k_degree(const int* __restrict__ ei, int* __restrict__ deg) {
  int e = blockIdx.x * 256 + threadIdx.x;
  if (e < NE) atomicAdd(&deg[ei[NE + e]], 1);
}

__global__ __launch_bounds__(1024) void k_scan(const int* __restrict__ deg,
                                               int* __restrict__ rowstart) {
  __shared__ int sm[1024];
  int carry = 0;
  if (threadIdx.x == 0) rowstart[0] = 0;
  for (int base = 0; base < NN; base += 1024) {
    int i = base + threadIdx.x;
    int v = (i < NN) ? deg[i] : 0;
    sm[threadIdx.x] = v;
    __syncthreads();
    for (int off = 1; off < 1024; off <<= 1) {
      int t = (threadIdx.x >= off) ? sm[threadIdx.x - off] : 0;
      __syncthreads();
      sm[threadIdx.x] += t;
      __syncthreads();
    }
    if (i < NN) rowstart[i + 1] = carry + sm[threadIdx.x];  // inclusive -> rowstart[i+1]
    carry += sm[1023];
    __syncthreads();
  }
}

__global__ void k_scatter(const int* __restrict__ ei, const int* __restrict__ rowstart,
                          int* __restrict__ cursor, int* __restrict__ srcp,
                          int* __restrict__ dstp) {
  int e = blockIdx.x * 256 + threadIdx.x;
  if (e >= NE) return;
  int s = ei[e], d = ei[NE + e];
  int pos = rowstart[d] + atomicAdd(&cursor[d], 1);
  srcp[pos] = s; dstp[pos] = d;
}

// ---------------- edge logits: logit[pos][h] = att_h . lrelu(xl[s]+xr[d]) -----
__global__ __launch_bounds__(256) void k_edge(const float* __restrict__ xl,
    const float* __restrict__ xr, const int* __restrict__ srcp,
    const int* __restrict__ dstp, const float* __restrict__ att,
    float* __restrict__ logit)
{
  int pos = blockIdx.x * 2 + (threadIdx.x >> 7);
  int t = threadIdx.x & 127;     // channel (h = t>>5, c = t&31)
  if (pos >= NE) return;
  int s = srcp[pos], d = dstp[pos];
  float v = xl[(size_t)s*128 + t] + xr[(size_t)d*128 + t];
  v = v > 0.f ? v : 0.2f * v;
  v *= att[t];
  #pragma unroll
  for (int off = 16; off > 0; off >>= 1) v += __shfl_xor(v, off);
  if ((t & 31) == 0) logit[(size_t)pos*4 + (t >> 5)] = v;
}

// ---------------- per-node softmax + aggregate + bias + elu -------------------
__global__ __launch_bounds__(128) void k_node(const float* __restrict__ xl,
    const float* __restrict__ logit, const int* __restrict__ srcp,
    const int* __restrict__ rowstart, const float* __restrict__ bias,
    float* __restrict__ out)
{
  int n = blockIdx.x;
  int t = threadIdx.x;       // channel
  int h = t >> 5;            // head
  int r0 = rowstart[n], r1 = rowstart[n + 1];
  // online softmax stats (all 32 lanes of a head group compute redundantly;
  // logit load is a 32-lane broadcast)
  float m = -1e30f, ssum = 0.f;
  for (int j = r0; j < r1; ++j) {
    float l = logit[(size_t)j*4 + h];
    float mn = fmaxf(m, l);
    ssum = ssum * __expf(m - mn) + __expf(l - mn);
    m = mn;
  }
  float acc = 0.f;
  for (int j = r0; j < r1; ++j) {
    float l = logit[(size_t)j*4 + h];
    float p = __expf(l - m);
    acc += p * xl[(size_t)srcp[j]*128 + t];   // coalesced 512B gather per edge
  }
  float o = acc / (ssum + 1e-16f) + bias[t];
  o = o > 0.f ? o : (__expf(o) - 1.f);        // both GAT layers are followed by elu
  out[(size_t)n*128 + t] = o;
}

// diagnostic: if ws is too small, report its size via out[0] instead of faulting
__global__ void k_report_ws(float* out, int out_size, float wsz) {
  int i = blockIdx.x * 256 + threadIdx.x;
  if (i < out_size) out[i] = (i == 0) ? wsz : 0.f;
}

// -----------------------------------------------------------------------------
extern "C" void kernel_launch(void* const* d_in, const int* in_sizes, int n_in,
                              void* d_out, int out_size, void* d_ws, size_t ws_size,
                              hipStream_t stream)
{
  const float* x    = (const float*)d_in[0];
  const int*   ei   = (const int*)d_in[1];     // int32! [2,E] row-major
  const float* Wp   = (const float*)d_in[2];  const float* bp    = (const float*)d_in[3];
  const float* Wl1  = (const float*)d_in[4];  const float* bl1   = (const float*)d_in[5];
  const float* Wr1  = (const float*)d_in[6];  const float* br1   = (const float*)d_in[7];
  const float* att1 = (const float*)d_in[8];  const float* bias1 = (const float*)d_in[9];
  const float* Wl2  = (const float*)d_in[10]; const float* bl2   = (const float*)d_in[11];
  const float* Wr2  = (const float*)d_in[12]; const float* br2   = (const float*)d_in[13];
  const float* att2 = (const float*)d_in[14]; const float* bias2 = (const float*)d_in[15];
  const float* W1   = (const float*)d_in[16]; const float* b1    = (const float*)d_in[17];
  const float* W2   = (const float*)d_in[18]; const float* b2    = (const float*)d_in[19];
  float* out = (float*)d_out;

  // workspace layout (bytes); total 122,200,004
  constexpr size_t NEED = 122200004;
  if (ws_size < NEED) {
    k_report_ws<<<(out_size + 255) / 256, 256, 0, stream>>>(out, out_size, (float)ws_size);
    return;
  }
  char* ws = (char*)d_ws;
  float* h0    = (float*)(ws + 0);             // 50000*256 f32 (51.2 MB)
  float* h1    = h0;                           // 50000*128 (reuses h0 lower half)
  float* h2    = (float*)(ws + 25600000);      // 50000*128 (upper half of h0 buf)
  float* xl    = (float*)(ws + 51200000);      // 50000*128
  float* xr    = (float*)(ws + 76800000);      // 50000*128
  float* logit = (float*)(ws + 102400000);     // 800000*4
  float* h3    = logit;                        // 50000*32 (reuses logit after L2)
  int*   srcp  = (int*)(ws + 115200000);       // 800000
  int*   dstp  = (int*)(ws + 118400000);       // 800000
  int*   deg   = (int*)(ws + 121600000);       // 50000
  int*   curs  = (int*)(ws + 121800000);       // 50000
  int*   rowst = (int*)(ws + 122000000);       // 50001

  hipMemsetAsync(deg,  0, NN*sizeof(int), stream);
  hipMemsetAsync(curs, 0, NN*sizeof(int), stream);

  // CSR by destination
  k_degree <<<(NE+255)/256, 256, 0, stream>>>(ei, deg);
  k_scan   <<<1, 1024, 0, stream>>>(deg, rowst);
  k_scatter<<<(NE+255)/256, 256, 0, stream>>>(ei, rowst, curs, srcp, dstp);

  // h0 = elu(x @ Wp^T + bp)   [50000,512]x[256,512]^T
  dim3 g0((NN+63)/64, 4);
  gemm_nt<1><<<g0, 256, 0, stream>>>(x, Wp, bp, h0, NN, 256, 512);

  // ---- GAT layer 1 ----
  dim3 g1((NN+63)/64, 2);
  gemm_nt<0><<<g1, 256, 0, stream>>>(h0, Wl1, bl1, xl, NN, 128, 256);
  gemm_nt<0><<<g1, 256, 0, stream>>>(h0, Wr1, br1, xr, NN, 128, 256);
  k_edge<<<(NE+1)/2, 256, 0, stream>>>(xl, xr, srcp, dstp, att1, logit);
  k_node<<<NN, 128, 0, stream>>>(xl, logit, srcp, rowst, bias1, h1);

  // ---- GAT layer 2 ----
  gemm_nt<0><<<g1, 256, 0, stream>>>(h1, Wl2, bl2, xl, NN, 128, 128);
  gemm_nt<0><<<g1, 256, 0, stream>>>(h1, Wr2, br2, xr, NN, 128, 128);
  k_edge<<<(NE+1)/2, 256, 0, stream>>>(xl, xr, srcp, dstp, att2, logit);
  k_node<<<NN, 128, 0, stream>>>(xl, logit, srcp, rowst, bias2, h2);

  // ---- head MLP ----
  dim3 g3((NN+63)/64, 1);
  gemm_nt<1><<<g3, 256, 0, stream>>>(h2, W1, b1, h3, NN, 32, 128);   // M=32,K=128
  gemm_nt<0><<<g3, 256, 0, stream>>>(h3, W2, b2, out, NN, 10, 32);   // M=10,K=32
}

// Round 3
// 762.600 us; speedup vs baseline: 1.8160x; 1.8160x over previous
//
#include <hip/hip_runtime.h>
#include <cstdint>
#include <cstddef>

constexpr int NN = 50000;
constexpr int NE = 800000;

// ---------------- GEMM NT: C[N,M] = act(A[N,K] @ B[M,K]^T + bias) -------------
// BN=64 rows x BM=64 cols per block, BK=16, 256 threads, 4x4 micro-tile.
// ACT: 0 = none, 1 = elu
template<int ACT>
__global__ __launch_bounds__(256) void gemm_nt(const float* __restrict__ A,
    const float* __restrict__ B, const float* __restrict__ bias,
    float* __restrict__ C, int N, int M, int K)
{
  __shared__ float As[16][64];   // As[k][row]
  __shared__ float Bs[16][64];   // Bs[k][col]
  const int tid = threadIdx.x;
  const int tx = tid & 15, ty = tid >> 4;
  const int row0 = blockIdx.x * 64, col0 = blockIdx.y * 64;
  const int lr = tid >> 2;           // 0..63
  const int kq = (tid & 3) << 2;     // 0,4,8,12
  float acc[4][4] = {};
  for (int k0 = 0; k0 < K; k0 += 16) {
    float4 a = make_float4(0.f,0.f,0.f,0.f), b = make_float4(0.f,0.f,0.f,0.f);
    int gr = row0 + lr;
    if (gr < N) a = *(const float4*)(A + (size_t)gr * K + k0 + kq);
    int gc = col0 + lr;
    if (gc < M) b = *(const float4*)(B + (size_t)gc * K + k0 + kq);
    __syncthreads();   // protect previous iteration's LDS reads
    As[kq+0][lr]=a.x; As[kq+1][lr]=a.y; As[kq+2][lr]=a.z; As[kq+3][lr]=a.w;
    Bs[kq+0][lr]=b.x; Bs[kq+1][lr]=b.y; Bs[kq+2][lr]=b.z; Bs[kq+3][lr]=b.w;
    __syncthreads();
    #pragma unroll
    for (int k = 0; k < 16; ++k) {
      float4 av = *(const float4*)&As[k][ty*4];
      float4 bv = *(const float4*)&Bs[k][tx*4];
      float aa[4] = {av.x,av.y,av.z,av.w};
      float bb[4] = {bv.x,bv.y,bv.z,bv.w};
      #pragma unroll
      for (int i = 0; i < 4; ++i)
        #pragma unroll
        for (int j = 0; j < 4; ++j)
          acc[i][j] += aa[i]*bb[j];
    }
  }
  #pragma unroll
  for (int i = 0; i < 4; ++i) {
    int row = row0 + ty*4 + i;
    if (row >= N) continue;
    #pragma unroll
    for (int j = 0; j < 4; ++j) {
      int col = col0 + tx*4 + j;
      if (col >= M) continue;
      float v = acc[i][j] + bias[col];
      if (ACT == 1) v = v > 0.f ? v : (__expf(v) - 1.f);
      C[(size_t)row*M + col] = v;
    }
  }
}

// ---------------- CSR build (dst-sorted edge permutation) ---------------------
// edge_index arrives as int32 (harness converts integer inputs to int32).
__global__ void k_degree(const int* __restrict__ ei, int* __restrict__ deg) {
  int e = blockIdx.x * 256 + threadIdx.x;
  if (e < NE) atomicAdd(&deg[ei[NE + e]], 1);
}

// multi-block scan, pass 1: per-256-chunk inclusive scan into rowstart[i+1],
// chunk total into blocksum[b]
__global__ __launch_bounds__(256) void k_scan1(const int* __restrict__ deg,
    int* __restrict__ rowstart, int* __restrict__ blocksum) {
  __shared__ int sm[256];
  int b = blockIdx.x, t = threadIdx.x;
  int i = b * 256 + t;
  int v = (i < NN) ? deg[i] : 0;
  sm[t] = v;
  __syncthreads();
  #pragma unroll
  for (int off = 1; off < 256; off <<= 1) {
    int u = (t >= off) ? sm[t - off] : 0;
    __syncthreads();
    sm[t] += u;
    __syncthreads();
  }
  if (i < NN) rowstart[i + 1] = sm[t];
  if (t == 255) blocksum[b] = sm[255];
}

// pass 2: single block, exclusive scan of blocksum (nb <= 256)
__global__ __launch_bounds__(256) void k_scan2(int* __restrict__ blocksum, int nb) {
  __shared__ int sm[256];
  int t = threadIdx.x;
  int v = (t < nb) ? blocksum[t] : 0;
  sm[t] = v;
  __syncthreads();
  #pragma unroll
  for (int off = 1; off < 256; off <<= 1) {
    int u = (t >= off) ? sm[t - off] : 0;
    __syncthreads();
    sm[t] += u;
    __syncthreads();
  }
  if (t < nb) blocksum[t] = (t == 0) ? 0 : sm[t - 1];   // exclusive
}

// pass 3: add chunk offsets
__global__ __launch_bounds__(256) void k_scan3(int* __restrict__ rowstart,
    const int* __restrict__ blocksum) {
  int b = blockIdx.x, t = threadIdx.x;
  int i = b * 256 + t;
  if (i == 0) rowstart[0] = 0;
  if (i < NN) rowstart[i + 1] += blocksum[b];
}

__global__ void k_scatter(const int* __restrict__ ei, const int* __restrict__ rowstart,
                          int* __restrict__ cursor, int* __restrict__ srcp) {
  int e = blockIdx.x * 256 + threadIdx.x;
  if (e >= NE) return;
  int s = ei[e], d = ei[NE + e];
  int pos = rowstart[d] + atomicAdd(&cursor[d], 1);
  srcp[pos] = s;
}

// -------- fused GATv2 edge+node: online softmax over incoming edges ----------
// 1 block = 1 node, 128 threads = channels (head h = t>>5).
// Per edge: gather xl[src] row (coalesced 512B), logit via 32-lane butterfly,
// online-softmax update of (m, ssum, acc). Output: elu(acc/ssum + bias).
__global__ __launch_bounds__(128) void k_gat(const float* __restrict__ xl,
    const float* __restrict__ xr, const int* __restrict__ srcp,
    const int* __restrict__ rowstart, const float* __restrict__ att,
    const float* __restrict__ bias, float* __restrict__ out)
{
  int n = blockIdx.x;
  int t = threadIdx.x;
  int r0 = rowstart[n], r1 = rowstart[n + 1];
  float xr_v = xr[(size_t)n*128 + t];
  float att_v = att[t];
  float m = -1e30f, ssum = 0.f, acc = 0.f;
  for (int j = r0; j < r1; ++j) {
    float xs = xl[(size_t)srcp[j]*128 + t];
    float u = xs + xr_v;
    u = u > 0.f ? u : 0.2f * u;
    float l = u * att_v;
    #pragma unroll
    for (int off = 16; off > 0; off >>= 1) l += __shfl_xor(l, off);
    float mn = fmaxf(m, l);
    float scale = __expf(m - mn);      // 1 when max unchanged
    float p = __expf(l - mn);
    ssum = ssum * scale + p;
    acc  = acc  * scale + p * xs;
    m = mn;
  }
  float o = acc / (ssum + 1e-16f) + bias[t];
  o = o > 0.f ? o : (__expf(o) - 1.f);   // both GAT layers are followed by elu
  out[(size_t)n*128 + t] = o;
}

// diagnostic: if ws is too small, report its size via out[0] instead of faulting
__global__ void k_report_ws(float* out, int out_size, float wsz) {
  int i = blockIdx.x * 256 + threadIdx.x;
  if (i < out_size) out[i] = (i == 0) ? wsz : 0.f;
}

// -----------------------------------------------------------------------------
extern "C" void kernel_launch(void* const* d_in, const int* in_sizes, int n_in,
                              void* d_out, int out_size, void* d_ws, size_t ws_size,
                              hipStream_t stream)
{
  const float* x    = (const float*)d_in[0];
  const int*   ei   = (const int*)d_in[1];     // int32 [2,E] row-major
  const float* Wp   = (const float*)d_in[2];  const float* bp    = (const float*)d_in[3];
  const float* Wl1  = (const float*)d_in[4];  const float* bl1   = (const float*)d_in[5];
  const float* Wr1  = (const float*)d_in[6];  const float* br1   = (const float*)d_in[7];
  const float* att1 = (const float*)d_in[8];  const float* bias1 = (const float*)d_in[9];
  const float* Wl2  = (const float*)d_in[10]; const float* bl2   = (const float*)d_in[11];
  const float* Wr2  = (const float*)d_in[12]; const float* br2   = (const float*)d_in[13];
  const float* att2 = (const float*)d_in[14]; const float* bias2 = (const float*)d_in[15];
  const float* W1   = (const float*)d_in[16]; const float* b1    = (const float*)d_in[17];
  const float* W2   = (const float*)d_in[18]; const float* b2    = (const float*)d_in[19];
  float* out = (float*)d_out;

  // workspace layout (bytes)
  constexpr size_t NEED = 122300000;
  if (ws_size < NEED) {
    k_report_ws<<<(out_size + 255) / 256, 256, 0, stream>>>(out, out_size, (float)ws_size);
    return;
  }
  char* ws = (char*)d_ws;
  float* h0    = (float*)(ws + 0);             // 50000*256 f32 (51.2 MB)
  float* h1    = h0;                           // 50000*128 (reuses h0 lower half)
  float* h2    = (float*)(ws + 25600000);      // 50000*128 (upper half of h0 buf)
  float* xl    = (float*)(ws + 51200000);      // 50000*128
  float* xr    = (float*)(ws + 76800000);      // 50000*128
  float* h3    = (float*)(ws + 102400000);     // 50000*32
  int*   srcp  = (int*)(ws + 115200000);       // 800000
  int*   deg   = (int*)(ws + 121600000);       // 50000
  int*   curs  = (int*)(ws + 121800000);       // 50000
  int*   rowst = (int*)(ws + 122000000);       // 50001
  int*   bsum  = (int*)(ws + 122250000);       // 256

  hipMemsetAsync(deg,  0, NN*sizeof(int), stream);
  hipMemsetAsync(curs, 0, NN*sizeof(int), stream);

  // CSR by destination (multi-block scan)
  constexpr int NB = (NN + 255) / 256;  // 196
  k_degree <<<(NE+255)/256, 256, 0, stream>>>(ei, deg);
  k_scan1  <<<NB, 256, 0, stream>>>(deg, rowst, bsum);
  k_scan2  <<<1, 256, 0, stream>>>(bsum, NB);
  k_scan3  <<<NB, 256, 0, stream>>>(rowst, bsum);
  k_scatter<<<(NE+255)/256, 256, 0, stream>>>(ei, rowst, curs, srcp);

  // h0 = elu(x @ Wp^T + bp)   [50000,512]x[256,512]^T
  dim3 g0((NN+63)/64, 4);
  gemm_nt<1><<<g0, 256, 0, stream>>>(x, Wp, bp, h0, NN, 256, 512);

  // ---- GAT layer 1 ----
  dim3 g1((NN+63)/64, 2);
  gemm_nt<0><<<g1, 256, 0, stream>>>(h0, Wl1, bl1, xl, NN, 128, 256);
  gemm_nt<0><<<g1, 256, 0, stream>>>(h0, Wr1, br1, xr, NN, 128, 256);
  k_gat<<<NN, 128, 0, stream>>>(xl, xr, srcp, rowst, att1, bias1, h1);

  // ---- GAT layer 2 ----
  gemm_nt<0><<<g1, 256, 0, stream>>>(h1, Wl2, bl2, xl, NN, 128, 128);
  gemm_nt<0><<<g1, 256, 0, stream>>>(h1, Wr2, br2, xr, NN, 128, 128);
  k_gat<<<NN, 128, 0, stream>>>(xl, xr, srcp, rowst, att2, bias2, h2);

  // ---- head MLP ----
  dim3 g3((NN+63)/64, 1);
  gemm_nt<1><<<g3, 256, 0, stream>>>(h2, W1, b1, h3, NN, 32, 128);   // M=32,K=128
  gemm_nt<0><<<g3, 256, 0, stream>>>(h3, W2, b2, out, NN, 10, 32);   // M=10,K=32
}

// Round 4
// 574.390 us; speedup vs baseline: 2.4110x; 1.3277x over previous
//
#include <hip/hip_runtime.h>
#include <cstdint>
#include <cstddef>

constexpr int NN = 50000;
constexpr int NE = 800000;

typedef short bf16x8 __attribute__((ext_vector_type(8)));
typedef float f32x16 __attribute__((ext_vector_type(16)));

__device__ inline unsigned short f2bf(float f) {
  unsigned u = __float_as_uint(f);
  return (unsigned short)((u + 0x7FFFu + ((u >> 16) & 1u)) >> 16);
}
__device__ inline float bf2f(unsigned short h) {
  return __uint_as_float(((unsigned)h) << 16);
}

// ---- pre-transform weights W[M][K] fp32 -> frag-order bf16 hi/lo -------------
// idx = ((cb*(K/16)+kb)*64 + l)*8 + j ; col = cb*32+(l&31); k = kb*16+((l>>5)&1)*8+j
__global__ void k_wconv(const float* __restrict__ W, short* __restrict__ Bh,
                        short* __restrict__ Bl, int M, int K, int total) {
  int idx = blockIdx.x * 256 + threadIdx.x;
  if (idx >= total) return;
  int j = idx & 7;
  int l = (idx >> 3) & 63;
  int blk = idx >> 9;
  int nKB = K >> 4;
  int cb = blk / nKB, kb = blk - cb * nKB;
  int col = cb * 32 + (l & 31);
  int k = kb * 16 + ((l >> 5) & 1) * 8 + j;
  float v = (col < M) ? W[(size_t)col * K + k] : 0.f;
  unsigned short h = f2bf(v);
  Bh[idx] = (short)h;
  Bl[idx] = (short)f2bf(v - bf2f(h));
}

// ---- split-bf16 MFMA GEMM: C[N,M] = act(A @ W^T + bias) ----------------------
// BM=64, BN=128, 512 thr = 8 waves (2 row x 4 col), per-wave 32x32, BK=32.
// A fp32 row-major, converted hi/lo into fragment-order LDS (conflict-free).
// B pre-converted frag-order bf16 hi/lo in global (L2-hot). 3 MFMA per k-step.
template<int ACT>
__global__ __launch_bounds__(512) void gemm_mfma(const float* __restrict__ A,
    const short* __restrict__ Bh, const short* __restrict__ Bl,
    const float* __restrict__ bias, float* __restrict__ C,
    int N, int M, int K)
{
  __shared__ short Ah[4 * 64 * 8];   // [(rt*2+kk)][lane][j]
  __shared__ short Al[4 * 64 * 8];
  const int t = threadIdx.x;
  const int lane = t & 63;
  const int wid = t >> 6;
  const int wr = wid >> 2;           // 0..1 row-tile
  const int wc = wid & 3;            // 0..3 col-tile
  const int row0 = blockIdx.x * 64;
  const int col0 = blockIdx.y * 128;
  const int nKB = K >> 4;

  f32x16 acc = {};
  for (int k0 = 0; k0 < K; k0 += 32) {
    __syncthreads();
    if (t < 256) {
      int sr = t & 63, sg = t >> 6;          // sg: 8-k group 0..3
      float4 a0 = make_float4(0,0,0,0), a1 = make_float4(0,0,0,0);
      if (row0 + sr < N) {
        const float* p = A + (size_t)(row0 + sr) * K + k0 + sg * 8;
        a0 = *(const float4*)p;
        a1 = *(const float4*)(p + 4);
      }
      float vin[8] = {a0.x,a0.y,a0.z,a0.w,a1.x,a1.y,a1.z,a1.w};
      bf16x8 hv, lv;
      #pragma unroll
      for (int q = 0; q < 8; ++q) {
        unsigned short h = f2bf(vin[q]);
        hv[q] = (short)h;
        lv[q] = (short)f2bf(vin[q] - bf2f(h));
      }
      int sbase = (((sr >> 5) * 2 + (sg >> 1)) * 64 + (sr & 31) + 32 * (sg & 1)) * 8;
      *(bf16x8*)&Ah[sbase] = hv;
      *(bf16x8*)&Al[sbase] = lv;
    }
    __syncthreads();
    #pragma unroll
    for (int kk = 0; kk < 2; ++kk) {
      bf16x8 a_h = *(const bf16x8*)&Ah[((wr*2 + kk)*64 + lane)*8];
      bf16x8 a_l = *(const bf16x8*)&Al[((wr*2 + kk)*64 + lane)*8];
      int cb = (col0 >> 5) + wc;
      int kbg = (k0 >> 4) + kk;
      size_t bidx = ((size_t)(cb * nKB + kbg) * 64 + lane) * 8;
      bf16x8 b_h = *(const bf16x8*)&Bh[bidx];
      bf16x8 b_l = *(const bf16x8*)&Bl[bidx];
      acc = __builtin_amdgcn_mfma_f32_32x32x16_bf16(a_h, b_h, acc, 0, 0, 0);
      acc = __builtin_amdgcn_mfma_f32_32x32x16_bf16(a_l, b_h, acc, 0, 0, 0);
      acc = __builtin_amdgcn_mfma_f32_32x32x16_bf16(a_h, b_l, acc, 0, 0, 0);
    }
  }
  // epilogue: D layout col=lane&31, row=(reg&3)+8*(reg>>2)+4*(lane>>5)
  int cc = col0 + wc * 32 + (lane & 31);
  float bv = (cc < M) ? bias[cc] : 0.f;
  #pragma unroll
  for (int r = 0; r < 16; ++r) {
    int rr = row0 + wr * 32 + (r & 3) + 8 * (r >> 2) + 4 * (lane >> 5);
    if (rr < N && cc < M) {
      float v = acc[r] + bv;
      if (ACT) v = v > 0.f ? v : (__expf(v) - 1.f);
      C[(size_t)rr * M + cc] = v;
    }
  }
}

// ---------------- CSR build (dst-sorted edge permutation) ---------------------
__global__ void k_degree(const int* __restrict__ ei, int* __restrict__ deg) {
  int e = blockIdx.x * 256 + threadIdx.x;
  if (e < NE) atomicAdd(&deg[ei[NE + e]], 1);
}

__global__ __launch_bounds__(256) void k_scan1(const int* __restrict__ deg,
    int* __restrict__ rowstart, int* __restrict__ blocksum) {
  __shared__ int sm[256];
  int b = blockIdx.x, t = threadIdx.x;
  int i = b * 256 + t;
  int v = (i < NN) ? deg[i] : 0;
  sm[t] = v;
  __syncthreads();
  #pragma unroll
  for (int off = 1; off < 256; off <<= 1) {
    int u = (t >= off) ? sm[t - off] : 0;
    __syncthreads();
    sm[t] += u;
    __syncthreads();
  }
  if (i < NN) rowstart[i + 1] = sm[t];
  if (t == 255) blocksum[b] = sm[255];
}

__global__ __launch_bounds__(256) void k_scan2(int* __restrict__ blocksum, int nb) {
  __shared__ int sm[256];
  int t = threadIdx.x;
  int v = (t < nb) ? blocksum[t] : 0;
  sm[t] = v;
  __syncthreads();
  #pragma unroll
  for (int off = 1; off < 256; off <<= 1) {
    int u = (t >= off) ? sm[t - off] : 0;
    __syncthreads();
    sm[t] += u;
    __syncthreads();
  }
  if (t < nb) blocksum[t] = (t == 0) ? 0 : sm[t - 1];
}

__global__ __launch_bounds__(256) void k_scan3(int* __restrict__ rowstart,
    const int* __restrict__ blocksum) {
  int b = blockIdx.x, t = threadIdx.x;
  int i = b * 256 + t;
  if (i == 0) rowstart[0] = 0;
  if (i < NN) rowstart[i + 1] += blocksum[b];
}

__global__ void k_scatter(const int* __restrict__ ei, const int* __restrict__ rowstart,
                          int* __restrict__ cursor, int* __restrict__ srcp) {
  int e = blockIdx.x * 256 + threadIdx.x;
  if (e >= NE) return;
  int s = ei[e], d = ei[NE + e];
  int pos = rowstart[d] + atomicAdd(&cursor[d], 1);
  srcp[pos] = s;
}

// -------- fused GATv2 edge+node: online softmax over incoming edges ----------
__global__ __launch_bounds__(128) void k_gat(const float* __restrict__ xl,
    const float* __restrict__ xr, const int* __restrict__ srcp,
    const int* __restrict__ rowstart, const float* __restrict__ att,
    const float* __restrict__ bias, float* __restrict__ out)
{
  int n = blockIdx.x;
  int t = threadIdx.x;
  int r0 = rowstart[n], r1 = rowstart[n + 1];
  float xr_v = xr[(size_t)n*128 + t];
  float att_v = att[t];
  float m = -1e30f, ssum = 0.f, acc = 0.f;
  for (int j = r0; j < r1; ++j) {
    float xs = xl[(size_t)srcp[j]*128 + t];
    float u = xs + xr_v;
    u = u > 0.f ? u : 0.2f * u;
    float l = u * att_v;
    #pragma unroll
    for (int off = 16; off > 0; off >>= 1) l += __shfl_xor(l, off);
    float mn = fmaxf(m, l);
    float scale = __expf(m - mn);
    float p = __expf(l - mn);
    ssum = ssum * scale + p;
    acc  = acc  * scale + p * xs;
    m = mn;
  }
  float o = acc / (ssum + 1e-16f) + bias[t];
  o = o > 0.f ? o : (__expf(o) - 1.f);
  out[(size_t)n*128 + t] = o;
}

__global__ void k_report_ws(float* out, int out_size, float wsz) {
  int i = blockIdx.x * 256 + threadIdx.x;
  if (i < out_size) out[i] = (i == 0) ? wsz : 0.f;
}

// -----------------------------------------------------------------------------
extern "C" void kernel_launch(void* const* d_in, const int* in_sizes, int n_in,
                              void* d_out, int out_size, void* d_ws, size_t ws_size,
                              hipStream_t stream)
{
  const float* x    = (const float*)d_in[0];
  const int*   ei   = (const int*)d_in[1];     // int32 [2,E] row-major
  const float* Wp   = (const float*)d_in[2];  const float* bp    = (const float*)d_in[3];
  const float* Wl1  = (const float*)d_in[4];  const float* bl1   = (const float*)d_in[5];
  const float* Wr1  = (const float*)d_in[6];  const float* br1   = (const float*)d_in[7];
  const float* att1 = (const float*)d_in[8];  const float* bias1 = (const float*)d_in[9];
  const float* Wl2  = (const float*)d_in[10]; const float* bl2   = (const float*)d_in[11];
  const float* Wr2  = (const float*)d_in[12]; const float* br2   = (const float*)d_in[13];
  const float* att2 = (const float*)d_in[14]; const float* bias2 = (const float*)d_in[15];
  const float* W1   = (const float*)d_in[16]; const float* b1    = (const float*)d_in[17];
  const float* W2   = (const float*)d_in[18]; const float* b2    = (const float*)d_in[19];
  float* out = (float*)d_out;

  constexpr size_t NEED = 122300000;
  if (ws_size < NEED) {
    k_report_ws<<<(out_size + 255) / 256, 256, 0, stream>>>(out, out_size, (float)ws_size);
    return;
  }
  char* ws = (char*)d_ws;
  float* h0    = (float*)(ws + 0);             // 50000*256 f32
  float* h1    = h0;                           // reuse
  float* h2    = (float*)(ws + 25600000);
  float* xl    = (float*)(ws + 51200000);
  float* xr    = (float*)(ws + 76800000);
  float* h3    = (float*)(ws + 102400000);     // 50000*32 (ends 108.8MB)
  short* wb    = (short*)(ws + 108800000);     // weight hi/lo frag buffers (<1MB)
  int*   srcp  = (int*)(ws + 115200000);
  int*   deg   = (int*)(ws + 121600000);
  int*   curs  = (int*)(ws + 121800000);
  int*   rowst = (int*)(ws + 122000000);
  int*   bsum  = (int*)(ws + 122250000);

  // weight buffer carve (element offsets in shorts)
  short* Wph  = wb;            short* Wpl  = wb + 131072;
  short* Wl1h = wb + 262144;   short* Wl1l = wb + 294912;
  short* Wr1h = wb + 327680;   short* Wr1l = wb + 360448;
  short* Wl2h = wb + 393216;   short* Wl2l = wb + 409600;
  short* Wr2h = wb + 425984;   short* Wr2l = wb + 442368;
  short* W1h  = wb + 458752;   short* W1l  = wb + 475136;
  short* W2h  = wb + 491520;   short* W2l  = wb + 495616;

  hipMemsetAsync(deg,  0, NN*sizeof(int), stream);
  hipMemsetAsync(curs, 0, NN*sizeof(int), stream);

  // weight pre-transform (tiny)
  k_wconv<<<(131072+255)/256, 256, 0, stream>>>(Wp,  Wph,  Wpl,  256, 512, 131072);
  k_wconv<<<(32768+255)/256,  256, 0, stream>>>(Wl1, Wl1h, Wl1l, 128, 256, 32768);
  k_wconv<<<(32768+255)/256,  256, 0, stream>>>(Wr1, Wr1h, Wr1l, 128, 256, 32768);
  k_wconv<<<(16384+255)/256,  256, 0, stream>>>(Wl2, Wl2h, Wl2l, 128, 128, 16384);
  k_wconv<<<(16384+255)/256,  256, 0, stream>>>(Wr2, Wr2h, Wr2l, 128, 128, 16384);
  k_wconv<<<(16384+255)/256,  256, 0, stream>>>(W1,  W1h,  W1l,  32,  128, 16384);
  k_wconv<<<(4096+255)/256,   256, 0, stream>>>(W2,  W2h,  W2l,  10,  32,  4096);

  // CSR by destination
  constexpr int NB = (NN + 255) / 256;
  k_degree <<<(NE+255)/256, 256, 0, stream>>>(ei, deg);
  k_scan1  <<<NB, 256, 0, stream>>>(deg, rowst, bsum);
  k_scan2  <<<1, 256, 0, stream>>>(bsum, NB);
  k_scan3  <<<NB, 256, 0, stream>>>(rowst, bsum);
  k_scatter<<<(NE+255)/256, 256, 0, stream>>>(ei, rowst, curs, srcp);

  constexpr int GX = (NN + 63) / 64;  // 782

  // projection: h0 = elu(x @ Wp^T + bp), M=256, K=512
  gemm_mfma<1><<<dim3(GX, 2), 512, 0, stream>>>(x, Wph, Wpl, bp, h0, NN, 256, 512);

  // GAT layer 1
  gemm_mfma<0><<<dim3(GX, 1), 512, 0, stream>>>(h0, Wl1h, Wl1l, bl1, xl, NN, 128, 256);
  gemm_mfma<0><<<dim3(GX, 1), 512, 0, stream>>>(h0, Wr1h, Wr1l, br1, xr, NN, 128, 256);
  k_gat<<<NN, 128, 0, stream>>>(xl, xr, srcp, rowst, att1, bias1, h1);

  // GAT layer 2
  gemm_mfma<0><<<dim3(GX, 1), 512, 0, stream>>>(h1, Wl2h, Wl2l, bl2, xl, NN, 128, 128);
  gemm_mfma<0><<<dim3(GX, 1), 512, 0, stream>>>(h1, Wr2h, Wr2l, br2, xr, NN, 128, 128);
  k_gat<<<NN, 128, 0, stream>>>(xl, xr, srcp, rowst, att2, bias2, h2);

  // head MLP
  gemm_mfma<1><<<dim3(GX, 1), 512, 0, stream>>>(h2, W1h, W1l, b1, h3, NN, 32, 128);
  gemm_mfma<0><<<dim3(GX, 1), 512, 0, stream>>>(h3, W2h, W2l, b2, out, NN, 10, 32);
}

// Round 5
// 486.070 us; speedup vs baseline: 2.8491x; 1.1817x over previous
//
#include <hip/hip_runtime.h>
#include <cstdint>
#include <cstddef>

constexpr int NN = 50000;
constexpr int NE = 800000;

typedef short bf16x8 __attribute__((ext_vector_type(8)));
typedef float f32x16 __attribute__((ext_vector_type(16)));
typedef unsigned short ushort_t;

__device__ inline unsigned short f2bf(float f) {
  unsigned u = __float_as_uint(f);
  return (unsigned short)((u + 0x7FFFu + ((u >> 16) & 1u)) >> 16);
}
__device__ inline float bf2f(unsigned short h) {
  return __uint_as_float(((unsigned)h) << 16);
}
__device__ inline ushort_t f2h(float f) {
  _Float16 h = (_Float16)f;
  return __builtin_bit_cast(ushort_t, h);
}
__device__ inline float h2f(ushort_t u) {
  return (float)__builtin_bit_cast(_Float16, u);
}

// ---- pre-transform weights W[M][K] fp32 -> frag-order bf16 hi/lo -------------
// idx = ((cb*(K/16)+kb)*64 + l)*8 + j ; col = cb*32+(l&31); k = kb*16+((l>>5)&1)*8+j
__global__ void k_wconv(const float* __restrict__ W, short* __restrict__ Bh,
                        short* __restrict__ Bl, int M, int K, int total) {
  int idx = blockIdx.x * 256 + threadIdx.x;
  if (idx >= total) return;
  int j = idx & 7;
  int l = (idx >> 3) & 63;
  int blk = idx >> 9;
  int nKB = K >> 4;
  int cb = blk / nKB, kb = blk - cb * nKB;
  int col = cb * 32 + (l & 31);
  int k = kb * 16 + ((l >> 5) & 1) * 8 + j;
  float v = (col < M) ? W[(size_t)col * K + k] : 0.f;
  unsigned short h = f2bf(v);
  Bh[idx] = (short)h;
  Bl[idx] = (short)f2bf(v - bf2f(h));
}

// ---- split-bf16 MFMA GEMM: C[N,M] = act(A @ W^T + bias) ----------------------
// BM=64, BN=128, 512 thr = 8 waves (2 row x 4 col), per-wave 32x32, BK=32.
// A fp32 row-major, converted hi/lo into fragment-order LDS (conflict-free).
// B pre-converted frag-order bf16 hi/lo in global (L2-hot). 3 MFMA per k-step.
// H16: write fp16 output (for the gathered xl operand) instead of fp32.
template<int ACT, int H16>
__global__ __launch_bounds__(512) void gemm_mfma(const float* __restrict__ A,
    const short* __restrict__ Bh, const short* __restrict__ Bl,
    const float* __restrict__ bias, float* __restrict__ C,
    ushort_t* __restrict__ C16, int N, int M, int K)
{
  __shared__ short Ah[4 * 64 * 8];   // [(rt*2+kk)][lane][j]
  __shared__ short Al[4 * 64 * 8];
  const int t = threadIdx.x;
  const int lane = t & 63;
  const int wid = t >> 6;
  const int wr = wid >> 2;           // 0..1 row-tile
  const int wc = wid & 3;            // 0..3 col-tile
  const int row0 = blockIdx.x * 64;
  const int col0 = blockIdx.y * 128;
  const int nKB = K >> 4;

  f32x16 acc = {};
  for (int k0 = 0; k0 < K; k0 += 32) {
    __syncthreads();
    if (t < 256) {
      int sr = t & 63, sg = t >> 6;          // sg: 8-k group 0..3
      float4 a0 = make_float4(0,0,0,0), a1 = make_float4(0,0,0,0);
      if (row0 + sr < N) {
        const float* p = A + (size_t)(row0 + sr) * K + k0 + sg * 8;
        a0 = *(const float4*)p;
        a1 = *(const float4*)(p + 4);
      }
      float vin[8] = {a0.x,a0.y,a0.z,a0.w,a1.x,a1.y,a1.z,a1.w};
      bf16x8 hv, lv;
      #pragma unroll
      for (int q = 0; q < 8; ++q) {
        unsigned short h = f2bf(vin[q]);
        hv[q] = (short)h;
        lv[q] = (short)f2bf(vin[q] - bf2f(h));
      }
      int sbase = (((sr >> 5) * 2 + (sg >> 1)) * 64 + (sr & 31) + 32 * (sg & 1)) * 8;
      *(bf16x8*)&Ah[sbase] = hv;
      *(bf16x8*)&Al[sbase] = lv;
    }
    __syncthreads();
    #pragma unroll
    for (int kk = 0; kk < 2; ++kk) {
      bf16x8 a_h = *(const bf16x8*)&Ah[((wr*2 + kk)*64 + lane)*8];
      bf16x8 a_l = *(const bf16x8*)&Al[((wr*2 + kk)*64 + lane)*8];
      int cb = (col0 >> 5) + wc;
      int kbg = (k0 >> 4) + kk;
      size_t bidx = ((size_t)(cb * nKB + kbg) * 64 + lane) * 8;
      bf16x8 b_h = *(const bf16x8*)&Bh[bidx];
      bf16x8 b_l = *(const bf16x8*)&Bl[bidx];
      acc = __builtin_amdgcn_mfma_f32_32x32x16_bf16(a_h, b_h, acc, 0, 0, 0);
      acc = __builtin_amdgcn_mfma_f32_32x32x16_bf16(a_l, b_h, acc, 0, 0, 0);
      acc = __builtin_amdgcn_mfma_f32_32x32x16_bf16(a_h, b_l, acc, 0, 0, 0);
    }
  }
  // epilogue: D layout col=lane&31, row=(reg&3)+8*(reg>>2)+4*(lane>>5)
  int cc = col0 + wc * 32 + (lane & 31);
  float bv = (cc < M) ? bias[cc] : 0.f;
  #pragma unroll
  for (int r = 0; r < 16; ++r) {
    int rr = row0 + wr * 32 + (r & 3) + 8 * (r >> 2) + 4 * (lane >> 5);
    if (rr < N && cc < M) {
      float v = acc[r] + bv;
      if (ACT) v = v > 0.f ? v : (__expf(v) - 1.f);
      if (H16) C16[(size_t)rr * M + cc] = f2h(v);
      else     C[(size_t)rr * M + cc] = v;
    }
  }
}

// ---------------- CSR build (dst-sorted edge permutation) ---------------------
__global__ void k_degree(const int* __restrict__ ei, int* __restrict__ deg) {
  int e = blockIdx.x * 256 + threadIdx.x;
  if (e < NE) atomicAdd(&deg[ei[NE + e]], 1);
}

__global__ __launch_bounds__(256) void k_scan1(const int* __restrict__ deg,
    int* __restrict__ rowstart, int* __restrict__ blocksum) {
  __shared__ int sm[256];
  int b = blockIdx.x, t = threadIdx.x;
  int i = b * 256 + t;
  int v = (i < NN) ? deg[i] : 0;
  sm[t] = v;
  __syncthreads();
  #pragma unroll
  for (int off = 1; off < 256; off <<= 1) {
    int u = (t >= off) ? sm[t - off] : 0;
    __syncthreads();
    sm[t] += u;
    __syncthreads();
  }
  if (i < NN) rowstart[i + 1] = sm[t];
  if (t == 255) blocksum[b] = sm[255];
}

__global__ __launch_bounds__(256) void k_scan2(int* __restrict__ blocksum, int nb) {
  __shared__ int sm[256];
  int t = threadIdx.x;
  int v = (t < nb) ? blocksum[t] : 0;
  sm[t] = v;
  __syncthreads();
  #pragma unroll
  for (int off = 1; off < 256; off <<= 1) {
    int u = (t >= off) ? sm[t - off] : 0;
    __syncthreads();
    sm[t] += u;
    __syncthreads();
  }
  if (t < nb) blocksum[t] = (t == 0) ? 0 : sm[t - 1];
}

__global__ __launch_bounds__(256) void k_scan3(int* __restrict__ rowstart,
    const int* __restrict__ blocksum) {
  int b = blockIdx.x, t = threadIdx.x;
  int i = b * 256 + t;
  if (i == 0) rowstart[0] = 0;
  if (i < NN) rowstart[i + 1] += blocksum[b];
}

__global__ void k_scatter(const int* __restrict__ ei, const int* __restrict__ rowstart,
                          int* __restrict__ cursor, int* __restrict__ srcp) {
  int e = blockIdx.x * 256 + threadIdx.x;
  if (e >= NE) return;
  int s = ei[e], d = ei[NE + e];
  int pos = rowstart[d] + atomicAdd(&cursor[d], 1);
  srcp[pos] = s;
}

// -------- fused GATv2 edge+node: online softmax over incoming edges ----------
// 1 block = 1 node, 128 threads = channels (head h = t>>5).
// xl is an fp16 mirror (gathered 256B/edge); 4-deep load pipelining so 4
// independent row-gathers are in flight per wave before the first use.
__global__ __launch_bounds__(128) void k_gat(const ushort_t* __restrict__ xl,
    const float* __restrict__ xr, const int* __restrict__ srcp,
    const int* __restrict__ rowstart, const float* __restrict__ att,
    const float* __restrict__ bias, float* __restrict__ out)
{
  int n = blockIdx.x;
  int t = threadIdx.x;
  int r0 = rowstart[n], r1 = rowstart[n + 1];
  float xr_v = xr[(size_t)n*128 + t];
  float att_v = att[t];
  float m = -1e30f, ssum = 0.f, acc = 0.f;
  auto upd = [&](float xs) {
    float u = xs + xr_v;
    u = u > 0.f ? u : 0.2f * u;
    float l = u * att_v;
    #pragma unroll
    for (int off = 16; off > 0; off >>= 1) l += __shfl_xor(l, off);
    float mn = fmaxf(m, l);
    float scale = __expf(m - mn);
    float p = __expf(l - mn);
    ssum = ssum * scale + p;
    acc  = acc  * scale + p * xs;
    m = mn;
  };
  int j = r0;
  for (; j + 4 <= r1; j += 4) {
    int s0 = srcp[j], s1 = srcp[j+1], s2 = srcp[j+2], s3 = srcp[j+3];
    float x0 = h2f(xl[(size_t)s0*128 + t]);
    float x1 = h2f(xl[(size_t)s1*128 + t]);
    float x2 = h2f(xl[(size_t)s2*128 + t]);
    float x3 = h2f(xl[(size_t)s3*128 + t]);
    upd(x0); upd(x1); upd(x2); upd(x3);
  }
  if (j + 2 <= r1) {
    int s0 = srcp[j], s1 = srcp[j+1];
    float x0 = h2f(xl[(size_t)s0*128 + t]);
    float x1 = h2f(xl[(size_t)s1*128 + t]);
    upd(x0); upd(x1);
    j += 2;
  }
  if (j < r1) upd(h2f(xl[(size_t)srcp[j]*128 + t]));
  float o = acc / (ssum + 1e-16f) + bias[t];
  o = o > 0.f ? o : (__expf(o) - 1.f);
  out[(size_t)n*128 + t] = o;
}

__global__ void k_report_ws(float* out, int out_size, float wsz) {
  int i = blockIdx.x * 256 + threadIdx.x;
  if (i < out_size) out[i] = (i == 0) ? wsz : 0.f;
}

// -----------------------------------------------------------------------------
extern "C" void kernel_launch(void* const* d_in, const int* in_sizes, int n_in,
                              void* d_out, int out_size, void* d_ws, size_t ws_size,
                              hipStream_t stream)
{
  const float* x    = (const float*)d_in[0];
  const int*   ei   = (const int*)d_in[1];     // int32 [2,E] row-major
  const float* Wp   = (const float*)d_in[2];  const float* bp    = (const float*)d_in[3];
  const float* Wl1  = (const float*)d_in[4];  const float* bl1   = (const float*)d_in[5];
  const float* Wr1  = (const float*)d_in[6];  const float* br1   = (const float*)d_in[7];
  const float* att1 = (const float*)d_in[8];  const float* bias1 = (const float*)d_in[9];
  const float* Wl2  = (const float*)d_in[10]; const float* bl2   = (const float*)d_in[11];
  const float* Wr2  = (const float*)d_in[12]; const float* br2   = (const float*)d_in[13];
  const float* att2 = (const float*)d_in[14]; const float* bias2 = (const float*)d_in[15];
  const float* W1   = (const float*)d_in[16]; const float* b1    = (const float*)d_in[17];
  const float* W2   = (const float*)d_in[18]; const float* b2    = (const float*)d_in[19];
  float* out = (float*)d_out;

  constexpr size_t NEED = 122300000;
  if (ws_size < NEED) {
    k_report_ws<<<(out_size + 255) / 256, 256, 0, stream>>>(out, out_size, (float)ws_size);
    return;
  }
  char* ws = (char*)d_ws;
  float*    h0    = (float*)(ws + 0);             // 50000*256 f32
  float*    h1    = h0;                           // reuse
  float*    h2    = (float*)(ws + 25600000);
  ushort_t* xlh   = (ushort_t*)(ws + 51200000);   // fp16 mirror, 12.8 MB
  float*    xr    = (float*)(ws + 76800000);
  float*    h3    = (float*)(ws + 102400000);     // 50000*32
  short*    wb    = (short*)(ws + 108800000);     // weight hi/lo frag buffers (<1MB)
  int*      srcp  = (int*)(ws + 115200000);
  int*      deg   = (int*)(ws + 121600000);
  int*      curs  = (int*)(ws + 121800000);
  int*      rowst = (int*)(ws + 122000000);
  int*      bsum  = (int*)(ws + 122250000);

  // weight buffer carve (element offsets in shorts)
  short* Wph  = wb;            short* Wpl  = wb + 131072;
  short* Wl1h = wb + 262144;   short* Wl1l = wb + 294912;
  short* Wr1h = wb + 327680;   short* Wr1l = wb + 360448;
  short* Wl2h = wb + 393216;   short* Wl2l = wb + 409600;
  short* Wr2h = wb + 425984;   short* Wr2l = wb + 442368;
  short* W1h  = wb + 458752;   short* W1l  = wb + 475136;
  short* W2h  = wb + 491520;   short* W2l  = wb + 495616;

  hipMemsetAsync(deg,  0, NN*sizeof(int), stream);
  hipMemsetAsync(curs, 0, NN*sizeof(int), stream);

  // weight pre-transform (tiny)
  k_wconv<<<(131072+255)/256, 256, 0, stream>>>(Wp,  Wph,  Wpl,  256, 512, 131072);
  k_wconv<<<(32768+255)/256,  256, 0, stream>>>(Wl1, Wl1h, Wl1l, 128, 256, 32768);
  k_wconv<<<(32768+255)/256,  256, 0, stream>>>(Wr1, Wr1h, Wr1l, 128, 256, 32768);
  k_wconv<<<(16384+255)/256,  256, 0, stream>>>(Wl2, Wl2h, Wl2l, 128, 128, 16384);
  k_wconv<<<(16384+255)/256,  256, 0, stream>>>(Wr2, Wr2h, Wr2l, 128, 128, 16384);
  k_wconv<<<(16384+255)/256,  256, 0, stream>>>(W1,  W1h,  W1l,  32,  128, 16384);
  k_wconv<<<(4096+255)/256,   256, 0, stream>>>(W2,  W2h,  W2l,  10,  32,  4096);

  // CSR by destination
  constexpr int NB = (NN + 255) / 256;
  k_degree <<<(NE+255)/256, 256, 0, stream>>>(ei, deg);
  k_scan1  <<<NB, 256, 0, stream>>>(deg, rowst, bsum);
  k_scan2  <<<1, 256, 0, stream>>>(bsum, NB);
  k_scan3  <<<NB, 256, 0, stream>>>(rowst, bsum);
  k_scatter<<<(NE+255)/256, 256, 0, stream>>>(ei, rowst, curs, srcp);

  constexpr int GX = (NN + 63) / 64;  // 782

  // projection: h0 = elu(x @ Wp^T + bp), M=256, K=512
  gemm_mfma<1,0><<<dim3(GX, 2), 512, 0, stream>>>(x, Wph, Wpl, bp, h0, nullptr, NN, 256, 512);

  // GAT layer 1
  gemm_mfma<0,1><<<dim3(GX, 1), 512, 0, stream>>>(h0, Wl1h, Wl1l, bl1, nullptr, xlh, NN, 128, 256);
  gemm_mfma<0,0><<<dim3(GX, 1), 512, 0, stream>>>(h0, Wr1h, Wr1l, br1, xr, nullptr, NN, 128, 256);
  k_gat<<<NN, 128, 0, stream>>>(xlh, xr, srcp, rowst, att1, bias1, h1);

  // GAT layer 2
  gemm_mfma<0,1><<<dim3(GX, 1), 512, 0, stream>>>(h1, Wl2h, Wl2l, bl2, nullptr, xlh, NN, 128, 128);
  gemm_mfma<0,0><<<dim3(GX, 1), 512, 0, stream>>>(h1, Wr2h, Wr2l, br2, xr, nullptr, NN, 128, 128);
  k_gat<<<NN, 128, 0, stream>>>(xlh, xr, srcp, rowst, att2, bias2, h2);

  // head MLP
  gemm_mfma<1,0><<<dim3(GX, 1), 512, 0, stream>>>(h2, W1h, W1l, b1, h3, nullptr, NN, 32, 128);
  gemm_mfma<0,0><<<dim3(GX, 1), 512, 0, stream>>>(h3, W2h, W2l, b2, out, nullptr, NN, 10, 32);
}

// Round 6
// 470.292 us; speedup vs baseline: 2.9447x; 1.0336x over previous
//
#include <hip/hip_runtime.h>
#include <cstdint>
#include <cstddef>

constexpr int NN = 50000;
constexpr int NE = 800000;

typedef short bf16x8 __attribute__((ext_vector_type(8)));
typedef short short4v __attribute__((ext_vector_type(4)));
typedef float f32x16 __attribute__((ext_vector_type(16)));
typedef unsigned short ushort_t;

__device__ inline unsigned short f2bf(float f) {
  unsigned u = __float_as_uint(f);
  return (unsigned short)((u + 0x7FFFu + ((u >> 16) & 1u)) >> 16);
}
__device__ inline float bf2f(unsigned short h) {
  return __uint_as_float(((unsigned)h) << 16);
}
__device__ inline ushort_t f2h(float f) {
  _Float16 h = (_Float16)f;
  return __builtin_bit_cast(ushort_t, h);
}
__device__ inline float h2f(ushort_t u) {
  return (float)__builtin_bit_cast(_Float16, u);
}

// ---- pre-transform weights W[M][K] fp32 -> frag-order bf16 hi/lo -------------
// idx = ((cb*(K/16)+kb)*64 + l)*8 + j ; col = cb*32+(l&31); k = kb*16+((l>>5)&1)*8+j
__global__ void k_wconv(const float* __restrict__ W, short* __restrict__ Bh,
                        short* __restrict__ Bl, int M, int K, int total) {
  int idx = blockIdx.x * 256 + threadIdx.x;
  if (idx >= total) return;
  int j = idx & 7;
  int l = (idx >> 3) & 63;
  int blk = idx >> 9;
  int nKB = K >> 4;
  int cb = blk / nKB, kb = blk - cb * nKB;
  int col = cb * 32 + (l & 31);
  int k = kb * 16 + ((l >> 5) & 1) * 8 + j;
  float v = (col < M) ? W[(size_t)col * K + k] : 0.f;
  unsigned short h = f2bf(v);
  Bh[idx] = (short)h;
  Bl[idx] = (short)f2bf(v - bf2f(h));
}

// ---- split-bf16 MFMA GEMM, software-pipelined --------------------------------
// BM=64, BN=128, 512 thr = 8 waves (2 row x 4 col), per-wave 32x32, BK=32.
// Double-buffered LDS A-tile (hi/lo, fragment order); B pre-converted frag-order
// in global (L2-hot), prefetched into named regs one step ahead. One barrier
// per K-step; global-load latency hides under the MFMA phase.
template<int ACT, int H16>
__global__ __launch_bounds__(512) void gemm_mfma(const float* __restrict__ A,
    const short* __restrict__ Bh, const short* __restrict__ Bl,
    const float* __restrict__ bias, float* __restrict__ C,
    ushort_t* __restrict__ C16, int N, int M, int K)
{
  __shared__ short Ah[2][2048];   // [buf][(rt*2+kk)*64*8 + lane*8 + j]
  __shared__ short Al[2][2048];
  const int t = threadIdx.x;
  const int lane = t & 63;
  const int wid = t >> 6;
  const int wr = wid >> 2;           // 0..1 row-tile
  const int wc = wid & 3;            // 0..3 col-tile
  const int row0 = blockIdx.x * 64;
  const int col0 = blockIdx.y * 128;
  const int nKB = K >> 4;
  const int nK = K >> 5;             // K-steps of 32

  // staging geometry: each of 512 threads handles 4 consecutive k of one row
  const int srow = t & 63;
  const int kq = (t >> 6) << 2;      // 0,4,...,28
  const int sbase = ((((srow >> 5) * 2 + (kq >> 4)) * 64) +
                     (srow & 31) + 32 * ((kq >> 3) & 1)) * 8 + (kq & 7);
  const bool arow_ok = (row0 + srow) < N;
  const float* aptr = A + (size_t)(row0 + srow) * K + kq;

  const int cb = (col0 >> 5) + wc;
  // B frag base for (kb16 block): ((cb*nKB + kb)*64 + lane)*8
  auto boff = [&](int kb) { return ((size_t)(cb * nKB + kb) * 64 + lane) * 8; };

  f32x16 acc = {};

  // ---- prologue: load + stage step 0; load B(0) regs ----
  float4 aR = make_float4(0, 0, 0, 0);
  if (arow_ok) aR = *(const float4*)aptr;
  bf16x8 bh0 = *(const bf16x8*)&Bh[boff(0)];
  bf16x8 bl0 = *(const bf16x8*)&Bl[boff(0)];
  bf16x8 bh1 = *(const bf16x8*)&Bh[boff(1)];
  bf16x8 bl1 = *(const bf16x8*)&Bl[boff(1)];
  {
    float vin[4] = {aR.x, aR.y, aR.z, aR.w};
    short4v hv, lv;
    #pragma unroll
    for (int q = 0; q < 4; ++q) {
      unsigned short h = f2bf(vin[q]);
      hv[q] = (short)h;
      lv[q] = (short)f2bf(vin[q] - bf2f(h));
    }
    *(short4v*)&Ah[0][sbase] = hv;
    *(short4v*)&Al[0][sbase] = lv;
  }
  __syncthreads();

  for (int ks = 0; ks < nK; ++ks) {
    const int cur = ks & 1;
    const int nxt = cur ^ 1;
    // ---- issue next-step global loads (clamped on last iter; discarded) ----
    const int ksn = (ks + 1 < nK) ? (ks + 1) : ks;
    float4 aN = make_float4(0, 0, 0, 0);
    if (arow_ok) aN = *(const float4*)(aptr + (size_t)ksn * 32);
    bf16x8 bh0n = *(const bf16x8*)&Bh[boff(ksn * 2)];
    bf16x8 bl0n = *(const bf16x8*)&Bl[boff(ksn * 2)];
    bf16x8 bh1n = *(const bf16x8*)&Bh[boff(ksn * 2 + 1)];
    bf16x8 bl1n = *(const bf16x8*)&Bl[boff(ksn * 2 + 1)];

    // ---- MFMA phase on buffer `cur` with current B regs ----
    bf16x8 a_h0 = *(const bf16x8*)&Ah[cur][((wr * 2 + 0) * 64 + lane) * 8];
    bf16x8 a_l0 = *(const bf16x8*)&Al[cur][((wr * 2 + 0) * 64 + lane) * 8];
    bf16x8 a_h1 = *(const bf16x8*)&Ah[cur][((wr * 2 + 1) * 64 + lane) * 8];
    bf16x8 a_l1 = *(const bf16x8*)&Al[cur][((wr * 2 + 1) * 64 + lane) * 8];
    acc = __builtin_amdgcn_mfma_f32_32x32x16_bf16(a_h0, bh0, acc, 0, 0, 0);
    acc = __builtin_amdgcn_mfma_f32_32x32x16_bf16(a_l0, bh0, acc, 0, 0, 0);
    acc = __builtin_amdgcn_mfma_f32_32x32x16_bf16(a_h0, bl0, acc, 0, 0, 0);
    acc = __builtin_amdgcn_mfma_f32_32x32x16_bf16(a_h1, bh1, acc, 0, 0, 0);
    acc = __builtin_amdgcn_mfma_f32_32x32x16_bf16(a_l1, bh1, acc, 0, 0, 0);
    acc = __builtin_amdgcn_mfma_f32_32x32x16_bf16(a_h1, bl1, acc, 0, 0, 0);

    // ---- stage next tile into buffer `nxt` (waits on aN here, after MFMAs) --
    if (ks + 1 < nK) {
      float vin[4] = {aN.x, aN.y, aN.z, aN.w};
      short4v hv, lv;
      #pragma unroll
      for (int q = 0; q < 4; ++q) {
        unsigned short h = f2bf(vin[q]);
        hv[q] = (short)h;
        lv[q] = (short)f2bf(vin[q] - bf2f(h));
      }
      *(short4v*)&Ah[nxt][sbase] = hv;
      *(short4v*)&Al[nxt][sbase] = lv;
    }
    bh0 = bh0n; bl0 = bl0n; bh1 = bh1n; bl1 = bl1n;
    __syncthreads();
  }

  // epilogue: D layout col=lane&31, row=(reg&3)+8*(reg>>2)+4*(lane>>5)
  int cc = col0 + wc * 32 + (lane & 31);
  float bv = (cc < M) ? bias[cc] : 0.f;
  #pragma unroll
  for (int r = 0; r < 16; ++r) {
    int rr = row0 + wr * 32 + (r & 3) + 8 * (r >> 2) + 4 * (lane >> 5);
    if (rr < N && cc < M) {
      float v = acc[r] + bv;
      if (ACT) v = v > 0.f ? v : (__expf(v) - 1.f);
      if (H16) C16[(size_t)rr * M + cc] = f2h(v);
      else     C[(size_t)rr * M + cc] = v;
    }
  }
}

// ---------------- CSR build (dst-sorted edge permutation) ---------------------
__global__ void k_degree(const int* __restrict__ ei, int* __restrict__ deg) {
  int e = blockIdx.x * 256 + threadIdx.x;
  if (e < NE) atomicAdd(&deg[ei[NE + e]], 1);
}

__global__ __launch_bounds__(256) void k_scan1(const int* __restrict__ deg,
    int* __restrict__ rowstart, int* __restrict__ blocksum) {
  __shared__ int sm[256];
  int b = blockIdx.x, t = threadIdx.x;
  int i = b * 256 + t;
  int v = (i < NN) ? deg[i] : 0;
  sm[t] = v;
  __syncthreads();
  #pragma unroll
  for (int off = 1; off < 256; off <<= 1) {
    int u = (t >= off) ? sm[t - off] : 0;
    __syncthreads();
    sm[t] += u;
    __syncthreads();
  }
  if (i < NN) rowstart[i + 1] = sm[t];
  if (t == 255) blocksum[b] = sm[255];
}

__global__ __launch_bounds__(256) void k_scan2(int* __restrict__ blocksum, int nb) {
  __shared__ int sm[256];
  int t = threadIdx.x;
  int v = (t < nb) ? blocksum[t] : 0;
  sm[t] = v;
  __syncthreads();
  #pragma unroll
  for (int off = 1; off < 256; off <<= 1) {
    int u = (t >= off) ? sm[t - off] : 0;
    __syncthreads();
    sm[t] += u;
    __syncthreads();
  }
  if (t < nb) blocksum[t] = (t == 0) ? 0 : sm[t - 1];
}

__global__ __launch_bounds__(256) void k_scan3(int* __restrict__ rowstart,
    const int* __restrict__ blocksum) {
  int b = blockIdx.x, t = threadIdx.x;
  int i = b * 256 + t;
  if (i == 0) rowstart[0] = 0;
  if (i < NN) rowstart[i + 1] += blocksum[b];
}

__global__ void k_scatter(const int* __restrict__ ei, const int* __restrict__ rowstart,
                          int* __restrict__ cursor, int* __restrict__ srcp) {
  int e = blockIdx.x * 256 + threadIdx.x;
  if (e >= NE) return;
  int s = ei[e], d = ei[NE + e];
  int pos = rowstart[d] + atomicAdd(&cursor[d], 1);
  srcp[pos] = s;
}

// -------- fused GATv2 edge+node: online softmax over incoming edges ----------
__global__ __launch_bounds__(128) void k_gat(const ushort_t* __restrict__ xl,
    const float* __restrict__ xr, const int* __restrict__ srcp,
    const int* __restrict__ rowstart, const float* __restrict__ att,
    const float* __restrict__ bias, float* __restrict__ out)
{
  int n = blockIdx.x;
  int t = threadIdx.x;
  int r0 = rowstart[n], r1 = rowstart[n + 1];
  float xr_v = xr[(size_t)n*128 + t];
  float att_v = att[t];
  float m = -1e30f, ssum = 0.f, acc = 0.f;
  auto upd = [&](float xs) {
    float u = xs + xr_v;
    u = u > 0.f ? u : 0.2f * u;
    float l = u * att_v;
    #pragma unroll
    for (int off = 16; off > 0; off >>= 1) l += __shfl_xor(l, off);
    float mn = fmaxf(m, l);
    float scale = __expf(m - mn);
    float p = __expf(l - mn);
    ssum = ssum * scale + p;
    acc  = acc  * scale + p * xs;
    m = mn;
  };
  int j = r0;
  for (; j + 4 <= r1; j += 4) {
    int s0 = srcp[j], s1 = srcp[j+1], s2 = srcp[j+2], s3 = srcp[j+3];
    float x0 = h2f(xl[(size_t)s0*128 + t]);
    float x1 = h2f(xl[(size_t)s1*128 + t]);
    float x2 = h2f(xl[(size_t)s2*128 + t]);
    float x3 = h2f(xl[(size_t)s3*128 + t]);
    upd(x0); upd(x1); upd(x2); upd(x3);
  }
  if (j + 2 <= r1) {
    int s0 = srcp[j], s1 = srcp[j+1];
    float x0 = h2f(xl[(size_t)s0*128 + t]);
    float x1 = h2f(xl[(size_t)s1*128 + t]);
    upd(x0); upd(x1);
    j += 2;
  }
  if (j < r1) upd(h2f(xl[(size_t)srcp[j]*128 + t]));
  float o = acc / (ssum + 1e-16f) + bias[t];
  o = o > 0.f ? o : (__expf(o) - 1.f);
  out[(size_t)n*128 + t] = o;
}

__global__ void k_report_ws(float* out, int out_size, float wsz) {
  int i = blockIdx.x * 256 + threadIdx.x;
  if (i < out_size) out[i] = (i == 0) ? wsz : 0.f;
}

// -----------------------------------------------------------------------------
extern "C" void kernel_launch(void* const* d_in, const int* in_sizes, int n_in,
                              void* d_out, int out_size, void* d_ws, size_t ws_size,
                              hipStream_t stream)
{
  const float* x    = (const float*)d_in[0];
  const int*   ei   = (const int*)d_in[1];     // int32 [2,E] row-major
  const float* Wp   = (const float*)d_in[2];  const float* bp    = (const float*)d_in[3];
  const float* Wl1  = (const float*)d_in[4];  const float* bl1   = (const float*)d_in[5];
  const float* Wr1  = (const float*)d_in[6];  const float* br1   = (const float*)d_in[7];
  const float* att1 = (const float*)d_in[8];  const float* bias1 = (const float*)d_in[9];
  const float* Wl2  = (const float*)d_in[10]; const float* bl2   = (const float*)d_in[11];
  const float* Wr2  = (const float*)d_in[12]; const float* br2   = (const float*)d_in[13];
  const float* att2 = (const float*)d_in[14]; const float* bias2 = (const float*)d_in[15];
  const float* W1   = (const float*)d_in[16]; const float* b1    = (const float*)d_in[17];
  const float* W2   = (const float*)d_in[18]; const float* b2    = (const float*)d_in[19];
  float* out = (float*)d_out;

  constexpr size_t NEED = 122300000;
  if (ws_size < NEED) {
    k_report_ws<<<(out_size + 255) / 256, 256, 0, stream>>>(out, out_size, (float)ws_size);
    return;
  }
  char* ws = (char*)d_ws;
  float*    h0    = (float*)(ws + 0);             // 50000*256 f32
  float*    h1    = h0;                           // reuse
  float*    h2    = (float*)(ws + 25600000);
  ushort_t* xlh   = (ushort_t*)(ws + 51200000);   // fp16 mirror, 12.8 MB
  float*    xr    = (float*)(ws + 76800000);
  float*    h3    = (float*)(ws + 102400000);     // 50000*32
  short*    wb    = (short*)(ws + 108800000);     // weight hi/lo frag buffers (<1MB)
  int*      srcp  = (int*)(ws + 115200000);
  int*      deg   = (int*)(ws + 121600000);
  int*      curs  = (int*)(ws + 121800000);
  int*      rowst = (int*)(ws + 122000000);
  int*      bsum  = (int*)(ws + 122250000);

  // weight buffer carve (element offsets in shorts)
  short* Wph  = wb;            short* Wpl  = wb + 131072;
  short* Wl1h = wb + 262144;   short* Wl1l = wb + 294912;
  short* Wr1h = wb + 327680;   short* Wr1l = wb + 360448;
  short* Wl2h = wb + 393216;   short* Wl2l = wb + 409600;
  short* Wr2h = wb + 425984;   short* Wr2l = wb + 442368;
  short* W1h  = wb + 458752;   short* W1l  = wb + 475136;
  short* W2h  = wb + 491520;   short* W2l  = wb + 495616;

  hipMemsetAsync(deg,  0, NN*sizeof(int), stream);
  hipMemsetAsync(curs, 0, NN*sizeof(int), stream);

  // weight pre-transform (tiny)
  k_wconv<<<(131072+255)/256, 256, 0, stream>>>(Wp,  Wph,  Wpl,  256, 512, 131072);
  k_wconv<<<(32768+255)/256,  256, 0, stream>>>(Wl1, Wl1h, Wl1l, 128, 256, 32768);
  k_wconv<<<(32768+255)/256,  256, 0, stream>>>(Wr1, Wr1h, Wr1l, 128, 256, 32768);
  k_wconv<<<(16384+255)/256,  256, 0, stream>>>(Wl2, Wl2h, Wl2l, 128, 128, 16384);
  k_wconv<<<(16384+255)/256,  256, 0, stream>>>(Wr2, Wr2h, Wr2l, 128, 128, 16384);
  k_wconv<<<(16384+255)/256,  256, 0, stream>>>(W1,  W1h,  W1l,  32,  128, 16384);
  k_wconv<<<(4096+255)/256,   256, 0, stream>>>(W2,  W2h,  W2l,  10,  32,  4096);

  // CSR by destination
  constexpr int NB = (NN + 255) / 256;
  k_degree <<<(NE+255)/256, 256, 0, stream>>>(ei, deg);
  k_scan1  <<<NB, 256, 0, stream>>>(deg, rowst, bsum);
  k_scan2  <<<1, 256, 0, stream>>>(bsum, NB);
  k_scan3  <<<NB, 256, 0, stream>>>(rowst, bsum);
  k_scatter<<<(NE+255)/256, 256, 0, stream>>>(ei, rowst, curs, srcp);

  constexpr int GX = (NN + 63) / 64;  // 782

  // projection: h0 = elu(x @ Wp^T + bp), M=256, K=512
  gemm_mfma<1,0><<<dim3(GX, 2), 512, 0, stream>>>(x, Wph, Wpl, bp, h0, nullptr, NN, 256, 512);

  // GAT layer 1
  gemm_mfma<0,1><<<dim3(GX, 1), 512, 0, stream>>>(h0, Wl1h, Wl1l, bl1, nullptr, xlh, NN, 128, 256);
  gemm_mfma<0,0><<<dim3(GX, 1), 512, 0, stream>>>(h0, Wr1h, Wr1l, br1, xr, nullptr, NN, 128, 256);
  k_gat<<<NN, 128, 0, stream>>>(xlh, xr, srcp, rowst, att1, bias1, h1);

  // GAT layer 2
  gemm_mfma<0,1><<<dim3(GX, 1), 512, 0, stream>>>(h1, Wl2h, Wl2l, bl2, nullptr, xlh, NN, 128, 128);
  gemm_mfma<0,0><<<dim3(GX, 1), 512, 0, stream>>>(h1, Wr2h, Wr2l, br2, xr, nullptr, NN, 128, 128);
  k_gat<<<NN, 128, 0, stream>>>(xlh, xr, srcp, rowst, att2, bias2, h2);

  // head MLP
  gemm_mfma<1,0><<<dim3(GX, 1), 512, 0, stream>>>(h2, W1h, W1l, b1, h3, nullptr, NN, 32, 128);
  gemm_mfma<0,0><<<dim3(GX, 1), 512, 0, stream>>>(h3, W2h, W2l, b2, out, nullptr, NN, 10, 32);
}

// Round 7
// 384.626 us; speedup vs baseline: 3.6005x; 1.2227x over previous
//
#include <hip/hip_runtime.h>
#include <cstdint>
#include <cstddef>

constexpr int NN = 50000;
constexpr int NE = 800000;

typedef short bf16x8 __attribute__((ext_vector_type(8)));
typedef short short4v __attribute__((ext_vector_type(4)));
typedef float f32x16 __attribute__((ext_vector_type(16)));
typedef _Float16 half4v __attribute__((ext_vector_type(4)));
typedef unsigned short ushort_t;

__device__ inline unsigned short f2bf(float f) {
  unsigned u = __float_as_uint(f);
  return (unsigned short)((u + 0x7FFFu + ((u >> 16) & 1u)) >> 16);
}
__device__ inline float bf2f(unsigned short h) {
  return __uint_as_float(((unsigned)h) << 16);
}
__device__ inline ushort_t f2h(float f) {
  _Float16 h = (_Float16)f;
  return __builtin_bit_cast(ushort_t, h);
}

// ---- pre-transform weights W[M][K] fp32 -> frag-order bf16 hi/lo -------------
// idx = ((cb*(K/16)+kb)*64 + l)*8 + j ; col = cb*32+(l&31); k = kb*16+((l>>5)&1)*8+j
__global__ void k_wconv(const float* __restrict__ W, short* __restrict__ Bh,
                        short* __restrict__ Bl, int M, int K, int total) {
  int idx = blockIdx.x * 256 + threadIdx.x;
  if (idx >= total) return;
  int j = idx & 7;
  int l = (idx >> 3) & 63;
  int blk = idx >> 9;
  int nKB = K >> 4;
  int cb = blk / nKB, kb = blk - cb * nKB;
  int col = cb * 32 + (l & 31);
  int k = kb * 16 + ((l >> 5) & 1) * 8 + j;
  float v = (col < M) ? W[(size_t)col * K + k] : 0.f;
  unsigned short h = f2bf(v);
  Bh[idx] = (short)h;
  Bl[idx] = (short)f2bf(v - bf2f(h));
}

// ---- split-bf16 MFMA GEMM, software-pipelined --------------------------------
// BM=64, BN=128, 512 thr = 8 waves (2 row x 4 col), per-wave 32x32, BK=32.
// Double-buffered LDS A-tile (hi/lo, fragment order); B pre-converted frag-order
// in global (L2-hot), prefetched into named regs one step ahead.
template<int ACT, int H16>
__global__ __launch_bounds__(512) void gemm_mfma(const float* __restrict__ A,
    const short* __restrict__ Bh, const short* __restrict__ Bl,
    const float* __restrict__ bias, float* __restrict__ C,
    ushort_t* __restrict__ C16, int N, int M, int K)
{
  __shared__ short Ah[2][2048];
  __shared__ short Al[2][2048];
  const int t = threadIdx.x;
  const int lane = t & 63;
  const int wid = t >> 6;
  const int wr = wid >> 2;
  const int wc = wid & 3;
  const int row0 = blockIdx.x * 64;
  const int col0 = blockIdx.y * 128;
  const int nKB = K >> 4;
  const int nK = K >> 5;

  const int srow = t & 63;
  const int kq = (t >> 6) << 2;
  const int sbase = ((((srow >> 5) * 2 + (kq >> 4)) * 64) +
                     (srow & 31) + 32 * ((kq >> 3) & 1)) * 8 + (kq & 7);
  const bool arow_ok = (row0 + srow) < N;
  const float* aptr = A + (size_t)(row0 + srow) * K + kq;

  const int cb = (col0 >> 5) + wc;
  auto boff = [&](int kb) { return ((size_t)(cb * nKB + kb) * 64 + lane) * 8; };

  f32x16 acc = {};

  float4 aR = make_float4(0, 0, 0, 0);
  if (arow_ok) aR = *(const float4*)aptr;
  bf16x8 bh0 = *(const bf16x8*)&Bh[boff(0)];
  bf16x8 bl0 = *(const bf16x8*)&Bl[boff(0)];
  bf16x8 bh1 = *(const bf16x8*)&Bh[boff(1)];
  bf16x8 bl1 = *(const bf16x8*)&Bl[boff(1)];
  {
    float vin[4] = {aR.x, aR.y, aR.z, aR.w};
    short4v hv, lv;
    #pragma unroll
    for (int q = 0; q < 4; ++q) {
      unsigned short h = f2bf(vin[q]);
      hv[q] = (short)h;
      lv[q] = (short)f2bf(vin[q] - bf2f(h));
    }
    *(short4v*)&Ah[0][sbase] = hv;
    *(short4v*)&Al[0][sbase] = lv;
  }
  __syncthreads();

  for (int ks = 0; ks < nK; ++ks) {
    const int cur = ks & 1;
    const int nxt = cur ^ 1;
    const int ksn = (ks + 1 < nK) ? (ks + 1) : ks;
    float4 aN = make_float4(0, 0, 0, 0);
    if (arow_ok) aN = *(const float4*)(aptr + (size_t)ksn * 32);
    bf16x8 bh0n = *(const bf16x8*)&Bh[boff(ksn * 2)];
    bf16x8 bl0n = *(const bf16x8*)&Bl[boff(ksn * 2)];
    bf16x8 bh1n = *(const bf16x8*)&Bh[boff(ksn * 2 + 1)];
    bf16x8 bl1n = *(const bf16x8*)&Bl[boff(ksn * 2 + 1)];

    bf16x8 a_h0 = *(const bf16x8*)&Ah[cur][((wr * 2 + 0) * 64 + lane) * 8];
    bf16x8 a_l0 = *(const bf16x8*)&Al[cur][((wr * 2 + 0) * 64 + lane) * 8];
    bf16x8 a_h1 = *(const bf16x8*)&Ah[cur][((wr * 2 + 1) * 64 + lane) * 8];
    bf16x8 a_l1 = *(const bf16x8*)&Al[cur][((wr * 2 + 1) * 64 + lane) * 8];
    acc = __builtin_amdgcn_mfma_f32_32x32x16_bf16(a_h0, bh0, acc, 0, 0, 0);
    acc = __builtin_amdgcn_mfma_f32_32x32x16_bf16(a_l0, bh0, acc, 0, 0, 0);
    acc = __builtin_amdgcn_mfma_f32_32x32x16_bf16(a_h0, bl0, acc, 0, 0, 0);
    acc = __builtin_amdgcn_mfma_f32_32x32x16_bf16(a_h1, bh1, acc, 0, 0, 0);
    acc = __builtin_amdgcn_mfma_f32_32x32x16_bf16(a_l1, bh1, acc, 0, 0, 0);
    acc = __builtin_amdgcn_mfma_f32_32x32x16_bf16(a_h1, bl1, acc, 0, 0, 0);

    if (ks + 1 < nK) {
      float vin[4] = {aN.x, aN.y, aN.z, aN.w};
      short4v hv, lv;
      #pragma unroll
      for (int q = 0; q < 4; ++q) {
        unsigned short h = f2bf(vin[q]);
        hv[q] = (short)h;
        lv[q] = (short)f2bf(vin[q] - bf2f(h));
      }
      *(short4v*)&Ah[nxt][sbase] = hv;
      *(short4v*)&Al[nxt][sbase] = lv;
    }
    bh0 = bh0n; bl0 = bl0n; bh1 = bh1n; bl1 = bl1n;
    __syncthreads();
  }

  int cc = col0 + wc * 32 + (lane & 31);
  float bv = (cc < M) ? bias[cc] : 0.f;
  #pragma unroll
  for (int r = 0; r < 16; ++r) {
    int rr = row0 + wr * 32 + (r & 3) + 8 * (r >> 2) + 4 * (lane >> 5);
    if (rr < N && cc < M) {
      float v = acc[r] + bv;
      if (ACT) v = v > 0.f ? v : (__expf(v) - 1.f);
      if (H16) C16[(size_t)rr * M + cc] = f2h(v);
      else     C[(size_t)rr * M + cc] = v;
    }
  }
}

// ---------------- CSR build (dst-sorted edge permutation) ---------------------
__global__ void k_degree(const int* __restrict__ ei, int* __restrict__ deg) {
  int e = blockIdx.x * 256 + threadIdx.x;
  if (e < NE) atomicAdd(&deg[ei[NE + e]], 1);
}

__global__ __launch_bounds__(256) void k_scan1(const int* __restrict__ deg,
    int* __restrict__ rowstart, int* __restrict__ blocksum) {
  __shared__ int sm[256];
  int b = blockIdx.x, t = threadIdx.x;
  int i = b * 256 + t;
  int v = (i < NN) ? deg[i] : 0;
  sm[t] = v;
  __syncthreads();
  #pragma unroll
  for (int off = 1; off < 256; off <<= 1) {
    int u = (t >= off) ? sm[t - off] : 0;
    __syncthreads();
    sm[t] += u;
    __syncthreads();
  }
  if (i < NN) rowstart[i + 1] = sm[t];
  if (t == 255) blocksum[b] = sm[255];
}

__global__ __launch_bounds__(256) void k_scan2(int* __restrict__ blocksum, int nb) {
  __shared__ int sm[256];
  int t = threadIdx.x;
  int v = (t < nb) ? blocksum[t] : 0;
  sm[t] = v;
  __syncthreads();
  #pragma unroll
  for (int off = 1; off < 256; off <<= 1) {
    int u = (t >= off) ? sm[t - off] : 0;
    __syncthreads();
    sm[t] += u;
    __syncthreads();
  }
  if (t < nb) blocksum[t] = (t == 0) ? 0 : sm[t - 1];
}

__global__ __launch_bounds__(256) void k_scan3(int* __restrict__ rowstart,
    const int* __restrict__ blocksum) {
  int b = blockIdx.x, t = threadIdx.x;
  int i = b * 256 + t;
  if (i == 0) rowstart[0] = 0;
  if (i < NN) rowstart[i + 1] += blocksum[b];
}

__global__ void k_scatter(const int* __restrict__ ei, const int* __restrict__ rowstart,
                          int* __restrict__ cursor, int* __restrict__ srcp) {
  int e = blockIdx.x * 256 + threadIdx.x;
  if (e >= NE) return;
  int s = ei[e], d = ei[NE + e];
  int pos = rowstart[d] + atomicAdd(&cursor[d], 1);
  srcp[pos] = s;
}

// -------- fused GATv2 edge+node, channel-packed: 32 lanes per node -----------
// lane c (0..31) owns channels 4c..4c+3 (all within head c>>3). Butterfly over
// 8 lanes (xor 1,2,4). 4-edge chunks: batched logits (ILP) + one fused online-
// softmax update. Block = 256 thr = 8 nodes.
__global__ __launch_bounds__(256) void k_gat(const ushort_t* __restrict__ xl,
    const float* __restrict__ xr, const int* __restrict__ srcp,
    const int* __restrict__ rowstart, const float* __restrict__ att,
    const float* __restrict__ bias, float* __restrict__ out)
{
  const int g = threadIdx.x >> 5;
  const int c = threadIdx.x & 31;
  const int n = blockIdx.x * 8 + g;
  const int r0 = rowstart[n], r1 = rowstart[n + 1];
  const float4 xrv = *(const float4*)(xr + (size_t)n * 128 + 4 * c);
  const float4 atv = *(const float4*)(att + 4 * c);

  float m = -1e30f, ssum = 0.f;
  float a0 = 0.f, a1 = 0.f, a2 = 0.f, a3 = 0.f;

  auto logit_of = [&](int s, float4& xs) -> float {
    half4v hv = *(const half4v*)(xl + (size_t)s * 128 + 4 * c);
    xs.x = (float)hv[0]; xs.y = (float)hv[1];
    xs.z = (float)hv[2]; xs.w = (float)hv[3];
    float u0 = xs.x + xrv.x; u0 = fmaxf(u0, 0.2f * u0);
    float u1 = xs.y + xrv.y; u1 = fmaxf(u1, 0.2f * u1);
    float u2 = xs.z + xrv.z; u2 = fmaxf(u2, 0.2f * u2);
    float u3 = xs.w + xrv.w; u3 = fmaxf(u3, 0.2f * u3);
    float l = u0 * atv.x + u1 * atv.y + u2 * atv.z + u3 * atv.w;
    l += __shfl_xor(l, 1);
    l += __shfl_xor(l, 2);
    l += __shfl_xor(l, 4);
    return l;
  };

  int j = r0;
  for (; j + 4 <= r1; j += 4) {
    int s0 = srcp[j], s1 = srcp[j + 1], s2 = srcp[j + 2], s3 = srcp[j + 3];
    float4 x0, x1, x2, x3;
    float l0 = logit_of(s0, x0);
    float l1 = logit_of(s1, x1);
    float l2 = logit_of(s2, x2);
    float l3 = logit_of(s3, x3);
    float mloc = fmaxf(fmaxf(l0, l1), fmaxf(l2, l3));
    float mn = fmaxf(m, mloc);
    float sc = __expf(m - mn);
    float p0 = __expf(l0 - mn), p1 = __expf(l1 - mn);
    float p2 = __expf(l2 - mn), p3 = __expf(l3 - mn);
    ssum = ssum * sc + ((p0 + p1) + (p2 + p3));
    a0 = a0 * sc + (p0 * x0.x + p1 * x1.x) + (p2 * x2.x + p3 * x3.x);
    a1 = a1 * sc + (p0 * x0.y + p1 * x1.y) + (p2 * x2.y + p3 * x3.y);
    a2 = a2 * sc + (p0 * x0.z + p1 * x1.z) + (p2 * x2.z + p3 * x3.z);
    a3 = a3 * sc + (p0 * x0.w + p1 * x1.w) + (p2 * x2.w + p3 * x3.w);
    m = mn;
  }
  for (; j < r1; ++j) {
    float4 xs;
    float l = logit_of(srcp[j], xs);
    float mn = fmaxf(m, l);
    float sc = __expf(m - mn);
    float p = __expf(l - mn);
    ssum = ssum * sc + p;
    a0 = a0 * sc + p * xs.x;
    a1 = a1 * sc + p * xs.y;
    a2 = a2 * sc + p * xs.z;
    a3 = a3 * sc + p * xs.w;
    m = mn;
  }

  const float4 bv = *(const float4*)(bias + 4 * c);
  float rinv = 1.f / (ssum + 1e-16f);
  float o0 = a0 * rinv + bv.x;
  float o1 = a1 * rinv + bv.y;
  float o2 = a2 * rinv + bv.z;
  float o3 = a3 * rinv + bv.w;
  o0 = o0 > 0.f ? o0 : (__expf(o0) - 1.f);
  o1 = o1 > 0.f ? o1 : (__expf(o1) - 1.f);
  o2 = o2 > 0.f ? o2 : (__expf(o2) - 1.f);
  o3 = o3 > 0.f ? o3 : (__expf(o3) - 1.f);
  *(float4*)(out + (size_t)n * 128 + 4 * c) = make_float4(o0, o1, o2, o3);
}

__global__ void k_report_ws(float* out, int out_size, float wsz) {
  int i = blockIdx.x * 256 + threadIdx.x;
  if (i < out_size) out[i] = (i == 0) ? wsz : 0.f;
}

// -----------------------------------------------------------------------------
extern "C" void kernel_launch(void* const* d_in, const int* in_sizes, int n_in,
                              void* d_out, int out_size, void* d_ws, size_t ws_size,
                              hipStream_t stream)
{
  const float* x    = (const float*)d_in[0];
  const int*   ei   = (const int*)d_in[1];     // int32 [2,E] row-major
  const float* Wp   = (const float*)d_in[2];  const float* bp    = (const float*)d_in[3];
  const float* Wl1  = (const float*)d_in[4];  const float* bl1   = (const float*)d_in[5];
  const float* Wr1  = (const float*)d_in[6];  const float* br1   = (const float*)d_in[7];
  const float* att1 = (const float*)d_in[8];  const float* bias1 = (const float*)d_in[9];
  const float* Wl2  = (const float*)d_in[10]; const float* bl2   = (const float*)d_in[11];
  const float* Wr2  = (const float*)d_in[12]; const float* br2   = (const float*)d_in[13];
  const float* att2 = (const float*)d_in[14]; const float* bias2 = (const float*)d_in[15];
  const float* W1   = (const float*)d_in[16]; const float* b1    = (const float*)d_in[17];
  const float* W2   = (const float*)d_in[18]; const float* b2    = (const float*)d_in[19];
  float* out = (float*)d_out;

  constexpr size_t NEED = 122300000;
  if (ws_size < NEED) {
    k_report_ws<<<(out_size + 255) / 256, 256, 0, stream>>>(out, out_size, (float)ws_size);
    return;
  }
  char* ws = (char*)d_ws;
  float*    h0    = (float*)(ws + 0);             // 50000*256 f32
  float*    h1    = h0;                           // reuse
  float*    h2    = (float*)(ws + 25600000);
  ushort_t* xlh   = (ushort_t*)(ws + 51200000);   // fp16 mirror, 12.8 MB
  float*    xr    = (float*)(ws + 76800000);
  float*    h3    = (float*)(ws + 102400000);     // 50000*32
  short*    wb    = (short*)(ws + 108800000);     // weight hi/lo frag buffers (<1MB)
  int*      srcp  = (int*)(ws + 115200000);
  int*      deg   = (int*)(ws + 121600000);
  int*      curs  = (int*)(ws + 121800000);
  int*      rowst = (int*)(ws + 122000000);
  int*      bsum  = (int*)(ws + 122250000);

  short* Wph  = wb;            short* Wpl  = wb + 131072;
  short* Wl1h = wb + 262144;   short* Wl1l = wb + 294912;
  short* Wr1h = wb + 327680;   short* Wr1l = wb + 360448;
  short* Wl2h = wb + 393216;   short* Wl2l = wb + 409600;
  short* Wr2h = wb + 425984;   short* Wr2l = wb + 442368;
  short* W1h  = wb + 458752;   short* W1l  = wb + 475136;
  short* W2h  = wb + 491520;   short* W2l  = wb + 495616;

  hipMemsetAsync(deg,  0, NN*sizeof(int), stream);
  hipMemsetAsync(curs, 0, NN*sizeof(int), stream);

  k_wconv<<<(131072+255)/256, 256, 0, stream>>>(Wp,  Wph,  Wpl,  256, 512, 131072);
  k_wconv<<<(32768+255)/256,  256, 0, stream>>>(Wl1, Wl1h, Wl1l, 128, 256, 32768);
  k_wconv<<<(32768+255)/256,  256, 0, stream>>>(Wr1, Wr1h, Wr1l, 128, 256, 32768);
  k_wconv<<<(16384+255)/256,  256, 0, stream>>>(Wl2, Wl2h, Wl2l, 128, 128, 16384);
  k_wconv<<<(16384+255)/256,  256, 0, stream>>>(Wr2, Wr2h, Wr2l, 128, 128, 16384);
  k_wconv<<<(16384+255)/256,  256, 0, stream>>>(W1,  W1h,  W1l,  32,  128, 16384);
  k_wconv<<<(4096+255)/256,   256, 0, stream>>>(W2,  W2h,  W2l,  10,  32,  4096);

  constexpr int NB = (NN + 255) / 256;
  k_degree <<<(NE+255)/256, 256, 0, stream>>>(ei, deg);
  k_scan1  <<<NB, 256, 0, stream>>>(deg, rowst, bsum);
  k_scan2  <<<1, 256, 0, stream>>>(bsum, NB);
  k_scan3  <<<NB, 256, 0, stream>>>(rowst, bsum);
  k_scatter<<<(NE+255)/256, 256, 0, stream>>>(ei, rowst, curs, srcp);

  constexpr int GX = (NN + 63) / 64;  // 782

  // projection: h0 = elu(x @ Wp^T + bp), M=256, K=512
  gemm_mfma<1,0><<<dim3(GX, 2), 512, 0, stream>>>(x, Wph, Wpl, bp, h0, nullptr, NN, 256, 512);

  // GAT layer 1
  gemm_mfma<0,1><<<dim3(GX, 1), 512, 0, stream>>>(h0, Wl1h, Wl1l, bl1, nullptr, xlh, NN, 128, 256);
  gemm_mfma<0,0><<<dim3(GX, 1), 512, 0, stream>>>(h0, Wr1h, Wr1l, br1, xr, nullptr, NN, 128, 256);
  k_gat<<<NN/8, 256, 0, stream>>>(xlh, xr, srcp, rowst, att1, bias1, h1);

  // GAT layer 2
  gemm_mfma<0,1><<<dim3(GX, 1), 512, 0, stream>>>(h1, Wl2h, Wl2l, bl2, nullptr, xlh, NN, 128, 128);
  gemm_mfma<0,0><<<dim3(GX, 1), 512, 0, stream>>>(h1, Wr2h, Wr2l, br2, xr, nullptr, NN, 128, 128);
  k_gat<<<NN/8, 256, 0, stream>>>(xlh, xr, srcp, rowst, att2, bias2, h2);

  // head MLP
  gemm_mfma<1,0><<<dim3(GX, 1), 512, 0, stream>>>(h2, W1h, W1l, b1, h3, nullptr, NN, 32, 128);
  gemm_mfma<0,0><<<dim3(GX, 1), 512, 0, stream>>>(h3, W2h, W2l, b2, out, nullptr, NN, 10, 32);
}